// Round 1
// baseline (694.384 us; speedup 1.0000x reference)
//
#include <hip/hip_runtime.h>
#include <hip/hip_bf16.h>
#include <stdint.h>

#define D_MODEL 768
#define NHEADS 12
#define HD 64
#define SEQ 4096
#define BATCH 2
#define MTOT (BATCH*SEQ)        // 8192
#define BHN (BATCH*NHEADS)      // 24

typedef __attribute__((ext_vector_type(8))) short short8;
typedef __attribute__((ext_vector_type(4))) float f32x4;
typedef __attribute__((ext_vector_type(4))) int i32x4;

__device__ inline unsigned short f2bf(float f) {
  union { float f; unsigned u; } v; v.f = f;
  unsigned r = (v.u + 0x7FFFu + ((v.u >> 16) & 1u)) >> 16;
  return (unsigned short)r;
}
__device__ inline float bf2f(unsigned short u) {
  union { unsigned u; float f; } v; v.u = ((unsigned)u) << 16;
  return v.f;
}

// ---------- fp32 -> bf16 conversion (vectorized x4) ----------
__global__ void k_f2bf4(const float* __restrict__ in, unsigned short* __restrict__ out, int n4) {
  int i = blockIdx.x * blockDim.x + threadIdx.x;
  if (i >= n4) return;
  float4 v = ((const float4*)in)[i];
  ushort4 o;
  o.x = f2bf(v.x); o.y = f2bf(v.y); o.z = f2bf(v.z); o.w = f2bf(v.w);
  ((ushort4*)out)[i] = o;
}

// ---------- RoPE cos/sin table: [SEQ][32] ----------
__global__ void k_ropetab(const int* __restrict__ pos, float* __restrict__ ct, float* __restrict__ st) {
  int i = blockIdx.x * blockDim.x + threadIdx.x;
  if (i >= SEQ*32) return;
  int s = i >> 5, j = i & 31;
  float p = (float)pos[s];
  const float L = 0.2878231366242557f;    // ln(10000)/32
  float freq = __expf(-L * (float)j);     // theta^(-2j/64)
  float a = p * freq;
  ct[i] = cosf(a);
  st[i] = sinf(a);
}

// ---------- QKV GEMM: [8192,768] @ W[768,768]^T, 128x128 tile, BK=32 ----------
// z=0 -> Q [B,H,S,64]; z=1 -> K [B,H,S,64]; z=2 -> V^T [B,H,64,S]
__global__ __launch_bounds__(256)
void k_gemm_qkv(const unsigned short* __restrict__ X,
                const unsigned short* __restrict__ Wq,
                const unsigned short* __restrict__ Wk,
                const unsigned short* __restrict__ Wv,
                unsigned short* __restrict__ Qp,
                unsigned short* __restrict__ Kp,
                unsigned short* __restrict__ VT)
{
  __shared__ __align__(16) unsigned short As[128*32];
  __shared__ __align__(16) unsigned short Bs[128*32];
  const int tid = threadIdx.x;
  const int wave = tid >> 6, lane = tid & 63;
  const int lr = lane & 15, lg = lane >> 4;
  const int wr = wave >> 1, wc = wave & 1;
  const int m0 = blockIdx.x * 128;
  const int n0 = blockIdx.y * 128;
  const int z  = blockIdx.z;
  const unsigned short* B = (z == 0) ? Wq : (z == 1) ? Wk : Wv;
  const int K = 768;

  f32x4 acc[4][4] = {};
  const int srow = tid >> 2, scol = (tid & 3) << 3;
  const unsigned short* ag = X + (size_t)(m0 + srow) * K + scol;
  const unsigned short* bg = B + (size_t)(n0 + srow) * K + scol;

  for (int k0 = 0; k0 < K; k0 += 32) {
    i32x4 a0 = *(const i32x4*)(ag + k0);
    i32x4 a1 = *(const i32x4*)(ag + (size_t)64*K + k0);
    i32x4 b0 = *(const i32x4*)(bg + k0);
    i32x4 b1 = *(const i32x4*)(bg + (size_t)64*K + k0);
    __syncthreads();
    *(i32x4*)&As[srow*32 + scol] = a0;
    *(i32x4*)&As[(srow+64)*32 + scol] = a1;
    *(i32x4*)&Bs[srow*32 + scol] = b0;
    *(i32x4*)&Bs[(srow+64)*32 + scol] = b1;
    __syncthreads();
    short8 af[4], bfr[4];
    #pragma unroll
    for (int i = 0; i < 4; ++i)
      af[i] = *(const short8*)&As[(wr*64 + i*16 + lr)*32 + lg*8];
    #pragma unroll
    for (int j = 0; j < 4; ++j)
      bfr[j] = *(const short8*)&Bs[(wc*64 + j*16 + lr)*32 + lg*8];
    #pragma unroll
    for (int i = 0; i < 4; ++i)
      #pragma unroll
      for (int j = 0; j < 4; ++j)
        acc[i][j] = __builtin_amdgcn_mfma_f32_16x16x32_bf16(af[i], bfr[j], acc[i][j], 0, 0, 0);
  }

  #pragma unroll
  for (int i = 0; i < 4; ++i)
    #pragma unroll
    for (int j = 0; j < 4; ++j)
      #pragma unroll
      for (int r = 0; r < 4; ++r) {
        int m = m0 + wr*64 + i*16 + lg*4 + r;   // C row
        int n = n0 + wc*64 + j*16 + lr;         // C col
        float v = acc[i][j][r];
        int bb = m >> 12, s = m & (SEQ-1);
        int h = n >> 6, d = n & (HD-1);
        if (z == 2) {
          VT[(((size_t)bb*NHEADS + h)*HD + d)*SEQ + s] = f2bf(v);
        } else {
          unsigned short* dst = (z == 0) ? Qp : Kp;
          dst[(((size_t)bb*NHEADS + h)*SEQ + s)*HD + d] = f2bf(v);
        }
      }
}

// ---------- WO GEMM: AO[8192,768] @ WO[768,768]^T -> fp32 out ----------
__global__ __launch_bounds__(256)
void k_gemm_wo(const unsigned short* __restrict__ X,
               const unsigned short* __restrict__ W,
               float* __restrict__ out)
{
  __shared__ __align__(16) unsigned short As[128*32];
  __shared__ __align__(16) unsigned short Bs[128*32];
  const int tid = threadIdx.x;
  const int wave = tid >> 6, lane = tid & 63;
  const int lr = lane & 15, lg = lane >> 4;
  const int wr = wave >> 1, wc = wave & 1;
  const int m0 = blockIdx.x * 128;
  const int n0 = blockIdx.y * 128;
  const int K = 768;

  f32x4 acc[4][4] = {};
  const int srow = tid >> 2, scol = (tid & 3) << 3;
  const unsigned short* ag = X + (size_t)(m0 + srow) * K + scol;
  const unsigned short* bg = W + (size_t)(n0 + srow) * K + scol;

  for (int k0 = 0; k0 < K; k0 += 32) {
    i32x4 a0 = *(const i32x4*)(ag + k0);
    i32x4 a1 = *(const i32x4*)(ag + (size_t)64*K + k0);
    i32x4 b0 = *(const i32x4*)(bg + k0);
    i32x4 b1 = *(const i32x4*)(bg + (size_t)64*K + k0);
    __syncthreads();
    *(i32x4*)&As[srow*32 + scol] = a0;
    *(i32x4*)&As[(srow+64)*32 + scol] = a1;
    *(i32x4*)&Bs[srow*32 + scol] = b0;
    *(i32x4*)&Bs[(srow+64)*32 + scol] = b1;
    __syncthreads();
    short8 af[4], bfr[4];
    #pragma unroll
    for (int i = 0; i < 4; ++i)
      af[i] = *(const short8*)&As[(wr*64 + i*16 + lr)*32 + lg*8];
    #pragma unroll
    for (int j = 0; j < 4; ++j)
      bfr[j] = *(const short8*)&Bs[(wc*64 + j*16 + lr)*32 + lg*8];
    #pragma unroll
    for (int i = 0; i < 4; ++i)
      #pragma unroll
      for (int j = 0; j < 4; ++j)
        acc[i][j] = __builtin_amdgcn_mfma_f32_16x16x32_bf16(af[i], bfr[j], acc[i][j], 0, 0, 0);
  }

  #pragma unroll
  for (int i = 0; i < 4; ++i)
    #pragma unroll
    for (int j = 0; j < 4; ++j)
      #pragma unroll
      for (int r = 0; r < 4; ++r) {
        int m = m0 + wr*64 + i*16 + lg*4 + r;
        int n = n0 + wc*64 + j*16 + lr;
        out[(size_t)m*D_MODEL + n] = acc[i][j][r];
      }
}

// ---------- RoPE in-place on Q (with 1/8 scale) and K ----------
__global__ void k_rope(unsigned short* __restrict__ Qp, unsigned short* __restrict__ Kp,
                       const float* __restrict__ ct, const float* __restrict__ st)
{
  int i = blockIdx.x * blockDim.x + threadIdx.x;  // < BHN*SEQ*32
  int j = i & 31;
  int s = (i >> 5) & (SEQ-1);
  int bh = i >> 17;
  size_t base = ((size_t)bh*SEQ + s)*HD + 2*j;
  float c = ct[(s<<5)+j], sn = st[(s<<5)+j];
  unsigned qv = *(const unsigned*)(Qp + base);
  float q0 = bf2f((unsigned short)(qv & 0xffffu));
  float q1 = bf2f((unsigned short)(qv >> 16));
  float a0 = (q0*c - q1*sn) * 0.125f;   // fold score scale 1/sqrt(64) into Q
  float a1 = (q1*c + q0*sn) * 0.125f;
  *(unsigned*)(Qp + base) = (unsigned)f2bf(a0) | ((unsigned)f2bf(a1) << 16);
  unsigned kv = *(const unsigned*)(Kp + base);
  float k0 = bf2f((unsigned short)(kv & 0xffffu));
  float k1 = bf2f((unsigned short)(kv >> 16));
  float b0 = k0*c - k1*sn;
  float b1 = k1*c + k0*sn;
  *(unsigned*)(Kp + base) = (unsigned)f2bf(b0) | ((unsigned)f2bf(b1) << 16);
}

// ---------- causal flash attention ----------
// grid (64, 24): 64 q-blocks of 64 rows, 24 (b,h). 4 waves/block, 16 q-rows/wave.
__global__ __launch_bounds__(256)
void k_attn(const unsigned short* __restrict__ Qp,
            const unsigned short* __restrict__ Kp,
            const unsigned short* __restrict__ VT,
            unsigned short* __restrict__ AO)
{
  __shared__ __align__(16) unsigned short Pl[4][16][80];  // per-wave P tile, pad 64->80
  const int tid = threadIdx.x;
  const int wave = tid >> 6, lane = tid & 63;
  const int lr = lane & 15, lg = lane >> 4;
  const int bh = blockIdx.y;
  const int b = bh / NHEADS, h = bh % NHEADS;
  const int qw = blockIdx.x * 64 + wave * 16;
  const unsigned short* Qh = Qp + (size_t)bh * SEQ * HD;
  const unsigned short* Kh = Kp + (size_t)bh * SEQ * HD;
  const unsigned short* Vh = VT + (size_t)bh * HD * SEQ;

  short8 qf[2];
  #pragma unroll
  for (int s = 0; s < 2; ++s)
    qf[s] = *(const short8*)(Qh + (size_t)(qw + lr)*HD + s*32 + lg*8);

  f32x4 o[4] = {};
  float m_r[4], l_r[4];
  #pragma unroll
  for (int r = 0; r < 4; ++r) { m_r[r] = -1e30f; l_r[r] = 0.f; }

  for (int kt = 0; kt <= qw + 15; kt += 64) {
    // QK^T: S[16 q x 64 k]
    f32x4 sf[4];
    #pragma unroll
    for (int cf = 0; cf < 4; ++cf) {
      f32x4 s4 = {0.f, 0.f, 0.f, 0.f};
      #pragma unroll
      for (int ks = 0; ks < 2; ++ks) {
        short8 kf = *(const short8*)(Kh + (size_t)(kt + cf*16 + lr)*HD + ks*32 + lg*8);
        s4 = __builtin_amdgcn_mfma_f32_16x16x32_bf16(qf[ks], kf, s4, 0, 0, 0);
      }
      sf[cf] = s4;
    }
    // causal mask (only tiles overlapping the diagonal)
    if (kt + 63 > qw) {
      #pragma unroll
      for (int cf = 0; cf < 4; ++cf)
        #pragma unroll
        for (int r = 0; r < 4; ++r) {
          int col = kt + cf*16 + lr;
          int row = qw + lg*4 + r;
          if (col > row) sf[cf][r] = -1e30f;
        }
    }
    // online softmax: row stats live per-reg, reduced over the 16 lanes of the lg group
    float tm[4];
    #pragma unroll
    for (int r = 0; r < 4; ++r)
      tm[r] = fmaxf(fmaxf(sf[0][r], sf[1][r]), fmaxf(sf[2][r], sf[3][r]));
    #pragma unroll
    for (int mk = 1; mk <= 8; mk <<= 1)
      #pragma unroll
      for (int r = 0; r < 4; ++r)
        tm[r] = fmaxf(tm[r], __shfl_xor(tm[r], mk));
    float corr[4];
    #pragma unroll
    for (int r = 0; r < 4; ++r) {
      float mn = fmaxf(m_r[r], tm[r]);
      corr[r] = __expf(m_r[r] - mn);
      m_r[r] = mn;
    }
    float rs[4] = {0.f, 0.f, 0.f, 0.f};
    #pragma unroll
    for (int cf = 0; cf < 4; ++cf)
      #pragma unroll
      for (int r = 0; r < 4; ++r) {
        float p = __expf(sf[cf][r] - m_r[r]);
        sf[cf][r] = p;
        rs[r] += p;
      }
    #pragma unroll
    for (int mk = 1; mk <= 8; mk <<= 1)
      #pragma unroll
      for (int r = 0; r < 4; ++r)
        rs[r] += __shfl_xor(rs[r], mk);
    #pragma unroll
    for (int r = 0; r < 4; ++r)
      l_r[r] = l_r[r]*corr[r] + rs[r];
    #pragma unroll
    for (int df = 0; df < 4; ++df)
      #pragma unroll
      for (int r = 0; r < 4; ++r)
        o[df][r] *= corr[r];
    // stage P: C-layout -> A-layout via wave-private LDS (no barrier needed)
    #pragma unroll
    for (int cf = 0; cf < 4; ++cf)
      #pragma unroll
      for (int r = 0; r < 4; ++r)
        Pl[wave][lg*4 + r][cf*16 + lr] = f2bf(sf[cf][r]);
    // PV: O += P[16x64] @ V[64x64]  (V^T rows are contiguous)
    #pragma unroll
    for (int ks = 0; ks < 2; ++ks) {
      short8 pf = *(const short8*)&Pl[wave][lr][ks*32 + lg*8];
      #pragma unroll
      for (int df = 0; df < 4; ++df) {
        short8 vf = *(const short8*)(Vh + (size_t)(df*16 + lr)*SEQ + kt + ks*32 + lg*8);
        o[df] = __builtin_amdgcn_mfma_f32_16x16x32_bf16(pf, vf, o[df], 0, 0, 0);
      }
    }
  }
  #pragma unroll
  for (int df = 0; df < 4; ++df)
    #pragma unroll
    for (int r = 0; r < 4; ++r) {
      int row = qw + lg*4 + r;
      int col = df*16 + lr;
      float v = o[df][r] / l_r[r];
      AO[((size_t)b*SEQ + row)*D_MODEL + h*HD + col] = f2bf(v);
    }
}

extern "C" void kernel_launch(void* const* d_in, const int* in_sizes, int n_in,
                              void* d_out, int out_size, void* d_ws, size_t ws_size,
                              hipStream_t stream)
{
  const float* x  = (const float*)d_in[0];
  const int* posi = (const int*)d_in[1];
  const float* wq = (const float*)d_in[2];
  const float* wk = (const float*)d_in[3];
  const float* wv = (const float*)d_in[4];
  const float* wo = (const float*)d_in[5];
  float* out = (float*)d_out;

  char* ws = (char*)d_ws;
  size_t off = 0;
  auto alloc = [&](size_t bytes) {
    char* p = ws + off;
    off += (bytes + 255) & ~(size_t)255;
    return p;
  };
  unsigned short* xb  = (unsigned short*)alloc((size_t)MTOT*D_MODEL*2);
  unsigned short* wqb = (unsigned short*)alloc((size_t)D_MODEL*D_MODEL*2);
  unsigned short* wkb = (unsigned short*)alloc((size_t)D_MODEL*D_MODEL*2);
  unsigned short* wvb = (unsigned short*)alloc((size_t)D_MODEL*D_MODEL*2);
  unsigned short* wob = (unsigned short*)alloc((size_t)D_MODEL*D_MODEL*2);
  unsigned short* Qb  = (unsigned short*)alloc((size_t)BHN*SEQ*HD*2);
  unsigned short* Kb  = (unsigned short*)alloc((size_t)BHN*SEQ*HD*2);
  unsigned short* VTb = (unsigned short*)alloc((size_t)BHN*HD*SEQ*2);
  unsigned short* AOb = (unsigned short*)alloc((size_t)MTOT*D_MODEL*2);
  float* ct = (float*)alloc((size_t)SEQ*32*4);
  float* st = (float*)alloc((size_t)SEQ*32*4);

  k_f2bf4<<<(MTOT*D_MODEL/4 + 255)/256, 256, 0, stream>>>(x, xb, MTOT*D_MODEL/4);
  k_f2bf4<<<(D_MODEL*D_MODEL/4 + 255)/256, 256, 0, stream>>>(wq, wqb, D_MODEL*D_MODEL/4);
  k_f2bf4<<<(D_MODEL*D_MODEL/4 + 255)/256, 256, 0, stream>>>(wk, wkb, D_MODEL*D_MODEL/4);
  k_f2bf4<<<(D_MODEL*D_MODEL/4 + 255)/256, 256, 0, stream>>>(wv, wvb, D_MODEL*D_MODEL/4);
  k_f2bf4<<<(D_MODEL*D_MODEL/4 + 255)/256, 256, 0, stream>>>(wo, wob, D_MODEL*D_MODEL/4);
  k_ropetab<<<(SEQ*32 + 255)/256, 256, 0, stream>>>(posi, ct, st);

  k_gemm_qkv<<<dim3(MTOT/128, D_MODEL/128, 3), 256, 0, stream>>>(xb, wqb, wkb, wvb, Qb, Kb, VTb);
  k_rope<<<(BHN*SEQ*32)/256, 256, 0, stream>>>(Qb, Kb, ct, st);
  k_attn<<<dim3(SEQ/64, BHN), 256, 0, stream>>>(Qb, Kb, VTb, AOb);
  k_gemm_wo<<<dim3(MTOT/128, D_MODEL/128), 256, 0, stream>>>(AOb, wob, out);
}

// Round 2
// 402.824 us; speedup vs baseline: 1.7238x; 1.7238x over previous
//
#include <hip/hip_runtime.h>
#include <hip/hip_bf16.h>
#include <stdint.h>

#define D_MODEL 768
#define NHEADS 12
#define HD 64
#define SEQ 4096
#define BATCH 2
#define MTOT (BATCH*SEQ)        // 8192
#define BHN (BATCH*NHEADS)      // 24

typedef __attribute__((ext_vector_type(8))) short short8;
typedef __attribute__((ext_vector_type(4))) float f32x4;
typedef __attribute__((ext_vector_type(4))) int i32x4;

__device__ inline unsigned short f2bf(float f) {
  union { float f; unsigned u; } v; v.f = f;
  unsigned r = (v.u + 0x7FFFu + ((v.u >> 16) & 1u)) >> 16;
  return (unsigned short)r;
}
__device__ inline float bf2f(unsigned short u) {
  union { unsigned u; float f; } v; v.u = ((unsigned)u) << 16;
  return v.f;
}

// ---------- fp32 -> bf16 conversion (vectorized x4) ----------
__global__ void k_f2bf4(const float* __restrict__ in, unsigned short* __restrict__ out, int n4) {
  int i = blockIdx.x * blockDim.x + threadIdx.x;
  if (i >= n4) return;
  float4 v = ((const float4*)in)[i];
  ushort4 o;
  o.x = f2bf(v.x); o.y = f2bf(v.y); o.z = f2bf(v.z); o.w = f2bf(v.w);
  ((ushort4*)out)[i] = o;
}

// ---------- RoPE cos/sin table: [SEQ][32] ----------
__global__ void k_ropetab(const int* __restrict__ pos, float* __restrict__ ct, float* __restrict__ st) {
  int i = blockIdx.x * blockDim.x + threadIdx.x;
  if (i >= SEQ*32) return;
  int s = i >> 5, j = i & 31;
  float p = (float)pos[s];
  const float L = 0.2878231366242557f;    // ln(10000)/32
  float freq = __expf(-L * (float)j);     // theta^(-2j/64)
  float a = p * freq;
  ct[i] = cosf(a);
  st[i] = sinf(a);
}

// ---------- QKV GEMM: [8192,768] @ W[768,768]^T, 128x128 tile, BK=32 ----------
// z=0 -> Q [B,H,S,64]; z=1 -> K [B,H,S,64]; z=2 -> V^T [B,H,64,S]
__global__ __launch_bounds__(256)
void k_gemm_qkv(const unsigned short* __restrict__ X,
                const unsigned short* __restrict__ Wq,
                const unsigned short* __restrict__ Wk,
                const unsigned short* __restrict__ Wv,
                unsigned short* __restrict__ Qp,
                unsigned short* __restrict__ Kp,
                unsigned short* __restrict__ VT)
{
  __shared__ __align__(16) unsigned short As[128*32];
  __shared__ __align__(16) unsigned short Bs[128*32];
  const int tid = threadIdx.x;
  const int wave = tid >> 6, lane = tid & 63;
  const int lr = lane & 15, lg = lane >> 4;
  const int wr = wave >> 1, wc = wave & 1;
  const int m0 = blockIdx.x * 128;
  const int n0 = blockIdx.y * 128;
  const int z  = blockIdx.z;
  const unsigned short* B = (z == 0) ? Wq : (z == 1) ? Wk : Wv;
  const int K = 768;

  f32x4 acc[4][4] = {};
  const int srow = tid >> 2, scol = (tid & 3) << 3;
  const unsigned short* ag = X + (size_t)(m0 + srow) * K + scol;
  const unsigned short* bg = B + (size_t)(n0 + srow) * K + scol;

  for (int k0 = 0; k0 < K; k0 += 32) {
    i32x4 a0 = *(const i32x4*)(ag + k0);
    i32x4 a1 = *(const i32x4*)(ag + (size_t)64*K + k0);
    i32x4 b0 = *(const i32x4*)(bg + k0);
    i32x4 b1 = *(const i32x4*)(bg + (size_t)64*K + k0);
    __syncthreads();
    *(i32x4*)&As[srow*32 + scol] = a0;
    *(i32x4*)&As[(srow+64)*32 + scol] = a1;
    *(i32x4*)&Bs[srow*32 + scol] = b0;
    *(i32x4*)&Bs[(srow+64)*32 + scol] = b1;
    __syncthreads();
    short8 af[4], bfr[4];
    #pragma unroll
    for (int i = 0; i < 4; ++i)
      af[i] = *(const short8*)&As[(wr*64 + i*16 + lr)*32 + lg*8];
    #pragma unroll
    for (int j = 0; j < 4; ++j)
      bfr[j] = *(const short8*)&Bs[(wc*64 + j*16 + lr)*32 + lg*8];
    #pragma unroll
    for (int i = 0; i < 4; ++i)
      #pragma unroll
      for (int j = 0; j < 4; ++j)
        acc[i][j] = __builtin_amdgcn_mfma_f32_16x16x32_bf16(af[i], bfr[j], acc[i][j], 0, 0, 0);
  }

  #pragma unroll
  for (int i = 0; i < 4; ++i)
    #pragma unroll
    for (int j = 0; j < 4; ++j)
      #pragma unroll
      for (int r = 0; r < 4; ++r) {
        int m = m0 + wr*64 + i*16 + lg*4 + r;   // C row
        int n = n0 + wc*64 + j*16 + lr;         // C col
        float v = acc[i][j][r];
        int bb = m >> 12, s = m & (SEQ-1);
        int h = n >> 6, d = n & (HD-1);
        if (z == 2) {
          VT[(((size_t)bb*NHEADS + h)*HD + d)*SEQ + s] = f2bf(v);
        } else {
          unsigned short* dst = (z == 0) ? Qp : Kp;
          dst[(((size_t)bb*NHEADS + h)*SEQ + s)*HD + d] = f2bf(v);
        }
      }
}

// ---------- WO GEMM: AO[8192,768] @ WO[768,768]^T -> fp32 out ----------
__global__ __launch_bounds__(256)
void k_gemm_wo(const unsigned short* __restrict__ X,
               const unsigned short* __restrict__ W,
               float* __restrict__ out)
{
  __shared__ __align__(16) unsigned short As[128*32];
  __shared__ __align__(16) unsigned short Bs[128*32];
  const int tid = threadIdx.x;
  const int wave = tid >> 6, lane = tid & 63;
  const int lr = lane & 15, lg = lane >> 4;
  const int wr = wave >> 1, wc = wave & 1;
  const int m0 = blockIdx.x * 128;
  const int n0 = blockIdx.y * 128;
  const int K = 768;

  f32x4 acc[4][4] = {};
  const int srow = tid >> 2, scol = (tid & 3) << 3;
  const unsigned short* ag = X + (size_t)(m0 + srow) * K + scol;
  const unsigned short* bg = W + (size_t)(n0 + srow) * K + scol;

  for (int k0 = 0; k0 < K; k0 += 32) {
    i32x4 a0 = *(const i32x4*)(ag + k0);
    i32x4 a1 = *(const i32x4*)(ag + (size_t)64*K + k0);
    i32x4 b0 = *(const i32x4*)(bg + k0);
    i32x4 b1 = *(const i32x4*)(bg + (size_t)64*K + k0);
    __syncthreads();
    *(i32x4*)&As[srow*32 + scol] = a0;
    *(i32x4*)&As[(srow+64)*32 + scol] = a1;
    *(i32x4*)&Bs[srow*32 + scol] = b0;
    *(i32x4*)&Bs[(srow+64)*32 + scol] = b1;
    __syncthreads();
    short8 af[4], bfr[4];
    #pragma unroll
    for (int i = 0; i < 4; ++i)
      af[i] = *(const short8*)&As[(wr*64 + i*16 + lr)*32 + lg*8];
    #pragma unroll
    for (int j = 0; j < 4; ++j)
      bfr[j] = *(const short8*)&Bs[(wc*64 + j*16 + lr)*32 + lg*8];
    #pragma unroll
    for (int i = 0; i < 4; ++i)
      #pragma unroll
      for (int j = 0; j < 4; ++j)
        acc[i][j] = __builtin_amdgcn_mfma_f32_16x16x32_bf16(af[i], bfr[j], acc[i][j], 0, 0, 0);
  }

  #pragma unroll
  for (int i = 0; i < 4; ++i)
    #pragma unroll
    for (int j = 0; j < 4; ++j)
      #pragma unroll
      for (int r = 0; r < 4; ++r) {
        int m = m0 + wr*64 + i*16 + lg*4 + r;
        int n = n0 + wc*64 + j*16 + lr;
        out[(size_t)m*D_MODEL + n] = acc[i][j][r];
      }
}

// ---------- RoPE in-place on Q (with 1/8 scale) and K ----------
__global__ void k_rope(unsigned short* __restrict__ Qp, unsigned short* __restrict__ Kp,
                       const float* __restrict__ ct, const float* __restrict__ st)
{
  int i = blockIdx.x * blockDim.x + threadIdx.x;  // < BHN*SEQ*32
  int j = i & 31;
  int s = (i >> 5) & (SEQ-1);
  int bh = i >> 17;
  size_t base = ((size_t)bh*SEQ + s)*HD + 2*j;
  float c = ct[(s<<5)+j], sn = st[(s<<5)+j];
  unsigned qv = *(const unsigned*)(Qp + base);
  float q0 = bf2f((unsigned short)(qv & 0xffffu));
  float q1 = bf2f((unsigned short)(qv >> 16));
  float a0 = (q0*c - q1*sn) * 0.125f;   // fold score scale 1/sqrt(64) into Q
  float a1 = (q1*c + q0*sn) * 0.125f;
  *(unsigned*)(Qp + base) = (unsigned)f2bf(a0) | ((unsigned)f2bf(a1) << 16);
  unsigned kv = *(const unsigned*)(Kp + base);
  float k0 = bf2f((unsigned short)(kv & 0xffffu));
  float k1 = bf2f((unsigned short)(kv >> 16));
  float b0 = k0*c - k1*sn;
  float b1 = k1*c + k0*sn;
  *(unsigned*)(Kp + base) = (unsigned)f2bf(b0) | ((unsigned)f2bf(b1) << 16);
}

// ---------- causal flash attention v2 ----------
// grid (32, 24): 32 q-tiles of 128 rows (launched in descending-work order), 24 (b,h).
// 8 waves/block, 16 q-rows/wave. K/V tiles staged in LDS (double-buffered, XOR-swizzled).
__global__ __launch_bounds__(512)
void k_attn(const unsigned short* __restrict__ Qp,
            const unsigned short* __restrict__ Kp,
            const unsigned short* __restrict__ VT,
            unsigned short* __restrict__ AO)
{
  __shared__ __align__(16) unsigned short Ks[2][64*64];   // [64 k-rows][64 d], swizzled
  __shared__ __align__(16) unsigned short Vs[2][64*64];   // [64 d-rows][64 k], swizzled
  __shared__ __align__(16) unsigned short Pl[8][16*72];   // per-wave P, pad 64->72 (144B rows)

  const int tid = threadIdx.x;
  const int wave = tid >> 6, lane = tid & 63;
  const int lr = lane & 15, lg = lane >> 4;
  const int bh = blockIdx.y;
  const int b = bh / NHEADS, h = bh % NHEADS;
  const int qb = (SEQ/128) - 1 - blockIdx.x;     // LPT: most work first
  const int qw = qb * 128 + wave * 16;
  const unsigned short* Qh = Qp + (size_t)bh * SEQ * HD;
  const unsigned short* Kh = Kp + (size_t)bh * SEQ * HD;
  const unsigned short* Vh = VT + (size_t)bh * HD * SEQ;

  const int nt   = 2*qb + 2;           // k-tiles this block processes
  const int myNt = (qw >> 6) + 1;      // k-tiles this wave is active for

  // staging: each of 512 threads moves 16B of K and 16B of V per tile
  const int srow = tid >> 3;           // 0..63
  const int scol = (tid & 7) * 8;      // element col
  const int swzb = (scol*2) ^ ((srow & 7) << 4);  // swizzled byte col within 128B row

  short8 qf[2];
  #pragma unroll
  for (int s = 0; s < 2; ++s)
    qf[s] = *(const short8*)(Qh + (size_t)(qw + lr)*HD + s*32 + lg*8);

  f32x4 o[4] = {};
  float m_r[4], l_r[4];
  #pragma unroll
  for (int r = 0; r < 4; ++r) { m_r[r] = -1e30f; l_r[r] = 0.f; }

  // prologue: stage tile 0 into buf 0
  i32x4 kreg = *(const i32x4*)(Kh + (size_t)srow*HD + scol);
  i32x4 vreg = *(const i32x4*)(Vh + (size_t)srow*SEQ + scol);
  *(i32x4*)((char*)Ks[0] + srow*128 + swzb) = kreg;
  *(i32x4*)((char*)Vs[0] + srow*128 + swzb) = vreg;
  __syncthreads();

  for (int kt = 0; kt < nt; ++kt) {
    const int cur = kt & 1;
    // issue next tile's global loads early (latency hides under compute)
    if (kt + 1 < nt) {
      kreg = *(const i32x4*)(Kh + (size_t)((kt+1)*64 + srow)*HD + scol);
      vreg = *(const i32x4*)(Vh + (size_t)srow*SEQ + (kt+1)*64 + scol);
    }
    if (kt < myNt) {
      // QK^T from LDS
      f32x4 sf[4];
      #pragma unroll
      for (int cf = 0; cf < 4; ++cf) {
        f32x4 s4 = {0.f, 0.f, 0.f, 0.f};
        #pragma unroll
        for (int ks = 0; ks < 2; ++ks) {
          const int kr = cf*16 + lr;
          short8 kf = *(const short8*)((const char*)Ks[cur] + kr*128 + ((ks*64 + lg*16) ^ ((kr & 7) << 4)));
          s4 = __builtin_amdgcn_mfma_f32_16x16x32_bf16(qf[ks], kf, s4, 0, 0, 0);
        }
        sf[cf] = s4;
      }
      // causal mask on diagonal tiles
      if (kt*64 + 63 > qw) {
        #pragma unroll
        for (int cf = 0; cf < 4; ++cf)
          #pragma unroll
          for (int r = 0; r < 4; ++r) {
            int col = kt*64 + cf*16 + lr;
            int row = qw + lg*4 + r;
            if (col > row) sf[cf][r] = -1e30f;
          }
      }
      // online softmax (row stats reduced over the 16 lanes of the lg group)
      float tm[4];
      #pragma unroll
      for (int r = 0; r < 4; ++r)
        tm[r] = fmaxf(fmaxf(sf[0][r], sf[1][r]), fmaxf(sf[2][r], sf[3][r]));
      #pragma unroll
      for (int mk = 1; mk <= 8; mk <<= 1)
        #pragma unroll
        for (int r = 0; r < 4; ++r)
          tm[r] = fmaxf(tm[r], __shfl_xor(tm[r], mk));
      float corr[4];
      #pragma unroll
      for (int r = 0; r < 4; ++r) {
        float mn = fmaxf(m_r[r], tm[r]);
        corr[r] = __expf(m_r[r] - mn);
        m_r[r] = mn;
      }
      float rs[4] = {0.f, 0.f, 0.f, 0.f};
      #pragma unroll
      for (int cf = 0; cf < 4; ++cf)
        #pragma unroll
        for (int r = 0; r < 4; ++r) {
          float p = __expf(sf[cf][r] - m_r[r]);
          sf[cf][r] = p;
          rs[r] += p;
        }
      #pragma unroll
      for (int mk = 1; mk <= 8; mk <<= 1)
        #pragma unroll
        for (int r = 0; r < 4; ++r)
          rs[r] += __shfl_xor(rs[r], mk);
      #pragma unroll
      for (int r = 0; r < 4; ++r)
        l_r[r] = l_r[r]*corr[r] + rs[r];
      #pragma unroll
      for (int df = 0; df < 4; ++df)
        #pragma unroll
        for (int r = 0; r < 4; ++r)
          o[df][r] *= corr[r];
      // P: C-layout -> A-layout via wave-private LDS
      #pragma unroll
      for (int cf = 0; cf < 4; ++cf)
        #pragma unroll
        for (int r = 0; r < 4; ++r)
          Pl[wave][(lg*4 + r)*72 + cf*16 + lr] = f2bf(sf[cf][r]);
      // PV from LDS
      #pragma unroll
      for (int ks = 0; ks < 2; ++ks) {
        short8 pf = *(const short8*)((const char*)Pl[wave] + lr*144 + ks*64 + lg*16);
        #pragma unroll
        for (int df = 0; df < 4; ++df) {
          const int dv = df*16 + lr;
          short8 vf = *(const short8*)((const char*)Vs[cur] + dv*128 + ((ks*64 + lg*16) ^ ((dv & 7) << 4)));
          o[df] = __builtin_amdgcn_mfma_f32_16x16x32_bf16(pf, vf, o[df], 0, 0, 0);
        }
      }
    }
    __syncthreads();                  // all waves done reading buf[cur]
    if (kt + 1 < nt) {
      *(i32x4*)((char*)Ks[cur ^ 1] + srow*128 + swzb) = kreg;
      *(i32x4*)((char*)Vs[cur ^ 1] + srow*128 + swzb) = vreg;
    }
    __syncthreads();                  // next buffer ready
  }

  #pragma unroll
  for (int df = 0; df < 4; ++df)
    #pragma unroll
    for (int r = 0; r < 4; ++r) {
      int row = qw + lg*4 + r;
      int col = df*16 + lr;
      float v = o[df][r] / l_r[r];
      AO[((size_t)b*SEQ + row)*D_MODEL + h*HD + col] = f2bf(v);
    }
}

extern "C" void kernel_launch(void* const* d_in, const int* in_sizes, int n_in,
                              void* d_out, int out_size, void* d_ws, size_t ws_size,
                              hipStream_t stream)
{
  const float* x  = (const float*)d_in[0];
  const int* posi = (const int*)d_in[1];
  const float* wq = (const float*)d_in[2];
  const float* wk = (const float*)d_in[3];
  const float* wv = (const float*)d_in[4];
  const float* wo = (const float*)d_in[5];
  float* out = (float*)d_out;

  char* ws = (char*)d_ws;
  size_t off = 0;
  auto alloc = [&](size_t bytes) {
    char* p = ws + off;
    off += (bytes + 255) & ~(size_t)255;
    return p;
  };
  unsigned short* xb  = (unsigned short*)alloc((size_t)MTOT*D_MODEL*2);
  unsigned short* wqb = (unsigned short*)alloc((size_t)D_MODEL*D_MODEL*2);
  unsigned short* wkb = (unsigned short*)alloc((size_t)D_MODEL*D_MODEL*2);
  unsigned short* wvb = (unsigned short*)alloc((size_t)D_MODEL*D_MODEL*2);
  unsigned short* wob = (unsigned short*)alloc((size_t)D_MODEL*D_MODEL*2);
  unsigned short* Qb  = (unsigned short*)alloc((size_t)BHN*SEQ*HD*2);
  unsigned short* Kb  = (unsigned short*)alloc((size_t)BHN*SEQ*HD*2);
  unsigned short* VTb = (unsigned short*)alloc((size_t)BHN*HD*SEQ*2);
  unsigned short* AOb = (unsigned short*)alloc((size_t)MTOT*D_MODEL*2);
  float* ct = (float*)alloc((size_t)SEQ*32*4);
  float* st = (float*)alloc((size_t)SEQ*32*4);

  k_f2bf4<<<(MTOT*D_MODEL/4 + 255)/256, 256, 0, stream>>>(x, xb, MTOT*D_MODEL/4);
  k_f2bf4<<<(D_MODEL*D_MODEL/4 + 255)/256, 256, 0, stream>>>(wq, wqb, D_MODEL*D_MODEL/4);
  k_f2bf4<<<(D_MODEL*D_MODEL/4 + 255)/256, 256, 0, stream>>>(wk, wkb, D_MODEL*D_MODEL/4);
  k_f2bf4<<<(D_MODEL*D_MODEL/4 + 255)/256, 256, 0, stream>>>(wv, wvb, D_MODEL*D_MODEL/4);
  k_f2bf4<<<(D_MODEL*D_MODEL/4 + 255)/256, 256, 0, stream>>>(wo, wob, D_MODEL*D_MODEL/4);
  k_ropetab<<<(SEQ*32 + 255)/256, 256, 0, stream>>>(posi, ct, st);

  k_gemm_qkv<<<dim3(MTOT/128, D_MODEL/128, 3), 256, 0, stream>>>(xb, wqb, wkb, wvb, Qb, Kb, VTb);
  k_rope<<<(BHN*SEQ*32)/256, 256, 0, stream>>>(Qb, Kb, ct, st);
  k_attn<<<dim3(SEQ/128, BHN), 512, 0, stream>>>(Qb, Kb, VTb, AOb);
  k_gemm_wo<<<dim3(MTOT/128, D_MODEL/128), 256, 0, stream>>>(AOb, wob, out);
}

// Round 4
// 237.421 us; speedup vs baseline: 2.9247x; 1.6967x over previous
//
#include <hip/hip_runtime.h>
#include <hip/hip_bf16.h>
#include <stdint.h>

#define D_MODEL 768
#define NHEADS 12
#define HD 64
#define SEQ 4096
#define BATCH 2
#define MTOT (BATCH*SEQ)        // 8192
#define BHN (BATCH*NHEADS)      // 24

typedef __attribute__((ext_vector_type(8))) short short8;
typedef __attribute__((ext_vector_type(4))) float f32x4;
typedef __attribute__((ext_vector_type(16))) float f32x16;
typedef __attribute__((ext_vector_type(4))) int i32x4;

__device__ inline unsigned short f2bf(float f) {
  union { float f; unsigned u; } v; v.f = f;
  unsigned r = (v.u + 0x7FFFu + ((v.u >> 16) & 1u)) >> 16;
  return (unsigned short)r;
}
__device__ inline float bf2f(unsigned short u) {
  union { unsigned u; float f; } v; v.u = ((unsigned)u) << 16;
  return v.f;
}
__device__ inline unsigned cvtpk_bf16(float lo, float hi) {
  unsigned r;
  asm("v_cvt_pk_bf16_f32 %0, %1, %2" : "=v"(r) : "v"(lo), "v"(hi));
  return r;
}
__device__ inline void perm32swap(unsigned &a, unsigned &b) {
  asm("v_permlane32_swap_b32 %0, %1" : "+v"(a), "+v"(b));
}

// ---------- fp32 -> bf16 conversion (vectorized x4) ----------
__global__ void k_f2bf4(const float* __restrict__ in, unsigned short* __restrict__ out, int n4) {
  int i = blockIdx.x * blockDim.x + threadIdx.x;
  if (i >= n4) return;
  float4 v = ((const float4*)in)[i];
  ushort4 o;
  o.x = f2bf(v.x); o.y = f2bf(v.y); o.z = f2bf(v.z); o.w = f2bf(v.w);
  ((ushort4*)out)[i] = o;
}

// ---------- RoPE cos/sin table: [SEQ][32] ----------
__global__ void k_ropetab(const int* __restrict__ pos, float* __restrict__ ct, float* __restrict__ st) {
  int i = blockIdx.x * blockDim.x + threadIdx.x;
  if (i >= SEQ*32) return;
  int s = i >> 5, j = i & 31;
  float p = (float)pos[s];
  const float L = 0.2878231366242557f;    // ln(10000)/32
  float freq = __expf(-L * (float)j);     // theta^(-2j/64)
  float a = p * freq;
  ct[i] = cosf(a);
  st[i] = sinf(a);
}

// ---------- QKV GEMM: [8192,768] @ W[768,768]^T, 128x128 tile, BK=32 ----------
__global__ __launch_bounds__(256)
void k_gemm_qkv(const unsigned short* __restrict__ X,
                const unsigned short* __restrict__ Wq,
                const unsigned short* __restrict__ Wk,
                const unsigned short* __restrict__ Wv,
                unsigned short* __restrict__ Qp,
                unsigned short* __restrict__ Kp,
                unsigned short* __restrict__ VT)
{
  __shared__ __align__(16) unsigned short As[128*32];
  __shared__ __align__(16) unsigned short Bs[128*32];
  const int tid = threadIdx.x;
  const int wave = tid >> 6, lane = tid & 63;
  const int lr = lane & 15, lg = lane >> 4;
  const int wr = wave >> 1, wc = wave & 1;
  const int m0 = blockIdx.x * 128;
  const int n0 = blockIdx.y * 128;
  const int z  = blockIdx.z;
  const unsigned short* B = (z == 0) ? Wq : (z == 1) ? Wk : Wv;
  const int K = 768;

  f32x4 acc[4][4] = {};
  const int srow = tid >> 2, scol = (tid & 3) << 3;
  const unsigned short* ag = X + (size_t)(m0 + srow) * K + scol;
  const unsigned short* bg = B + (size_t)(n0 + srow) * K + scol;

  for (int k0 = 0; k0 < K; k0 += 32) {
    i32x4 a0 = *(const i32x4*)(ag + k0);
    i32x4 a1 = *(const i32x4*)(ag + (size_t)64*K + k0);
    i32x4 b0 = *(const i32x4*)(bg + k0);
    i32x4 b1 = *(const i32x4*)(bg + (size_t)64*K + k0);
    __syncthreads();
    *(i32x4*)&As[srow*32 + scol] = a0;
    *(i32x4*)&As[(srow+64)*32 + scol] = a1;
    *(i32x4*)&Bs[srow*32 + scol] = b0;
    *(i32x4*)&Bs[(srow+64)*32 + scol] = b1;
    __syncthreads();
    short8 af[4], bfr[4];
    #pragma unroll
    for (int i = 0; i < 4; ++i)
      af[i] = *(const short8*)&As[(wr*64 + i*16 + lr)*32 + lg*8];
    #pragma unroll
    for (int j = 0; j < 4; ++j)
      bfr[j] = *(const short8*)&Bs[(wc*64 + j*16 + lr)*32 + lg*8];
    #pragma unroll
    for (int i = 0; i < 4; ++i)
      #pragma unroll
      for (int j = 0; j < 4; ++j)
        acc[i][j] = __builtin_amdgcn_mfma_f32_16x16x32_bf16(af[i], bfr[j], acc[i][j], 0, 0, 0);
  }

  #pragma unroll
  for (int i = 0; i < 4; ++i)
    #pragma unroll
    for (int j = 0; j < 4; ++j)
      #pragma unroll
      for (int r = 0; r < 4; ++r) {
        int m = m0 + wr*64 + i*16 + lg*4 + r;   // C row
        int n = n0 + wc*64 + j*16 + lr;         // C col
        float v = acc[i][j][r];
        int bb = m >> 12, s = m & (SEQ-1);
        int h = n >> 6, d = n & (HD-1);
        if (z == 2) {
          VT[(((size_t)bb*NHEADS + h)*HD + d)*SEQ + s] = f2bf(v);
        } else {
          unsigned short* dst = (z == 0) ? Qp : Kp;
          dst[(((size_t)bb*NHEADS + h)*SEQ + s)*HD + d] = f2bf(v);
        }
      }
}

// ---------- WO GEMM: AO[8192,768] @ WO[768,768]^T -> fp32 out ----------
__global__ __launch_bounds__(256)
void k_gemm_wo(const unsigned short* __restrict__ X,
               const unsigned short* __restrict__ W,
               float* __restrict__ out)
{
  __shared__ __align__(16) unsigned short As[128*32];
  __shared__ __align__(16) unsigned short Bs[128*32];
  const int tid = threadIdx.x;
  const int wave = tid >> 6, lane = tid & 63;
  const int lr = lane & 15, lg = lane >> 4;
  const int wr = wave >> 1, wc = wave & 1;
  const int m0 = blockIdx.x * 128;
  const int n0 = blockIdx.y * 128;
  const int K = 768;

  f32x4 acc[4][4] = {};
  const int srow = tid >> 2, scol = (tid & 3) << 3;
  const unsigned short* ag = X + (size_t)(m0 + srow) * K + scol;
  const unsigned short* bg = W + (size_t)(n0 + srow) * K + scol;

  for (int k0 = 0; k0 < K; k0 += 32) {
    i32x4 a0 = *(const i32x4*)(ag + k0);
    i32x4 a1 = *(const i32x4*)(ag + (size_t)64*K + k0);
    i32x4 b0 = *(const i32x4*)(bg + k0);
    i32x4 b1 = *(const i32x4*)(bg + (size_t)64*K + k0);
    __syncthreads();
    *(i32x4*)&As[srow*32 + scol] = a0;
    *(i32x4*)&As[(srow+64)*32 + scol] = a1;
    *(i32x4*)&Bs[srow*32 + scol] = b0;
    *(i32x4*)&Bs[(srow+64)*32 + scol] = b1;
    __syncthreads();
    short8 af[4], bfr[4];
    #pragma unroll
    for (int i = 0; i < 4; ++i)
      af[i] = *(const short8*)&As[(wr*64 + i*16 + lr)*32 + lg*8];
    #pragma unroll
    for (int j = 0; j < 4; ++j)
      bfr[j] = *(const short8*)&Bs[(wc*64 + j*16 + lr)*32 + lg*8];
    #pragma unroll
    for (int i = 0; i < 4; ++i)
      #pragma unroll
      for (int j = 0; j < 4; ++j)
        acc[i][j] = __builtin_amdgcn_mfma_f32_16x16x32_bf16(af[i], bfr[j], acc[i][j], 0, 0, 0);
  }

  #pragma unroll
  for (int i = 0; i < 4; ++i)
    #pragma unroll
    for (int j = 0; j < 4; ++j)
      #pragma unroll
      for (int r = 0; r < 4; ++r) {
        int m = m0 + wr*64 + i*16 + lg*4 + r;
        int n = n0 + wc*64 + j*16 + lr;
        out[(size_t)m*D_MODEL + n] = acc[i][j][r];
      }
}

// ---------- RoPE in-place on Q (with 1/8 scale) and K ----------
__global__ void k_rope(unsigned short* __restrict__ Qp, unsigned short* __restrict__ Kp,
                       const float* __restrict__ ct, const float* __restrict__ st)
{
  int i = blockIdx.x * blockDim.x + threadIdx.x;  // < BHN*SEQ*32
  int j = i & 31;
  int s = (i >> 5) & (SEQ-1);
  int bh = i >> 17;
  size_t base = ((size_t)bh*SEQ + s)*HD + 2*j;
  float c = ct[(s<<5)+j], sn = st[(s<<5)+j];
  unsigned qv = *(const unsigned*)(Qp + base);
  float q0 = bf2f((unsigned short)(qv & 0xffffu));
  float q1 = bf2f((unsigned short)(qv >> 16));
  float a0 = (q0*c - q1*sn) * 0.125f;   // fold score scale 1/sqrt(64) into Q
  float a1 = (q1*c + q0*sn) * 0.125f;
  *(unsigned*)(Qp + base) = (unsigned)f2bf(a0) | ((unsigned)f2bf(a1) << 16);
  unsigned kv = *(const unsigned*)(Kp + base);
  float k0 = bf2f((unsigned short)(kv & 0xffffu));
  float k1 = bf2f((unsigned short)(kv >> 16));
  float b0 = k0*c - k1*sn;
  float b1 = k1*c + k0*sn;
  *(unsigned*)(Kp + base) = (unsigned)f2bf(b0) | ((unsigned)f2bf(b1) << 16);
}

// ---------- causal flash attention v3: swapped-operand 32x32 MFMA ----------
// grid (32, 24): block = q-chunk pair (c, 63-c) of 64 rows each; 4 waves of 32 q-rows.
// Waves 0,1 -> chunk c; waves 2,3 -> chunk 63-c. Uniform 130 wave-tiles/block,
// 768 blocks = exactly 3/CU. S^T = mfma(K,Q); O^T = mfma(V,P): softmax & rescale
// fully per-lane (q = lane&31); P C->B relayout via cvt_pk_bf16 + permlane32_swap.
__global__ __launch_bounds__(256, 3)
void k_attn(const unsigned short* __restrict__ Qp,
            const unsigned short* __restrict__ Kp,
            const unsigned short* __restrict__ VT,
            unsigned short* __restrict__ AO)
{
  __shared__ __align__(16) unsigned short Ks[2][64*64];
  __shared__ __align__(16) unsigned short Vs[2][64*64];

  const int tid = threadIdx.x;
  const int wave = tid >> 6, lane = tid & 63;
  const int qcol = lane & 31, hi = lane >> 5;
  const int bh = blockIdx.y;
  const int b = bh / NHEADS, h = bh % NHEADS;
  const int cpair = blockIdx.x;                    // 0..31
  const int chunk = (wave < 2) ? cpair : 63 - cpair;
  const int qw = chunk * 64 + (wave & 1) * 32;     // this wave's 32 q-rows
  const int nt = 64 - cpair;                       // staged k-tiles (for hi chunk)
  const int myNt = qw / 64 + 1;                    // tiles this wave computes

  const unsigned short* Qh = Qp + (size_t)bh * SEQ * HD;
  const unsigned short* Kh = Kp + (size_t)bh * SEQ * HD;
  const unsigned short* Vh = VT + (size_t)bh * HD * SEQ;

  // Q fragment (B-operand): col=q=qcol, k-slot = hi*8+i per 16-d slice
  short8 qf[4];
  #pragma unroll
  for (int ds = 0; ds < 4; ++ds)
    qf[ds] = *(const short8*)(Qh + (size_t)(qw + qcol)*HD + ds*16 + hi*8);

  f32x16 o[2] = {};          // O^T accum: col=q=qcol, row d = dc*32 + (r&3)+8*(r>>2)+4*hi
  float m_r = -1e30f, l_r = 0.f;

  // staging: 256 threads x 4 x 16B per tile (K 8KB + V 8KB)
  const int srow = tid >> 3;                        // 0..31
  const int sseg = tid & 7;
  const int swz  = (sseg*16) ^ ((srow & 7) << 4);   // same for srow and srow+32

  { // prologue: tile 0 -> buf 0
    i32x4 k0 = *(const i32x4*)(Kh + (size_t)srow*HD + sseg*8);
    i32x4 k1 = *(const i32x4*)(Kh + (size_t)(srow+32)*HD + sseg*8);
    i32x4 v0 = *(const i32x4*)(Vh + (size_t)srow*SEQ + sseg*8);
    i32x4 v1 = *(const i32x4*)(Vh + (size_t)(srow+32)*SEQ + sseg*8);
    *(i32x4*)((char*)Ks[0] + srow*128 + swz) = k0;
    *(i32x4*)((char*)Ks[0] + (srow+32)*128 + swz) = k1;
    *(i32x4*)((char*)Vs[0] + srow*128 + swz) = v0;
    *(i32x4*)((char*)Vs[0] + (srow+32)*128 + swz) = v1;
  }
  __syncthreads();

  i32x4 pk0, pk1, pv0, pv1;
  for (int kt = 0; kt < nt; ++kt) {
    const int cur = kt & 1;
    if (kt + 1 < nt) {   // issue next tile's global loads early
      const size_t kb = (size_t)(kt+1) * 64;
      pk0 = *(const i32x4*)(Kh + (kb + srow)*HD + sseg*8);
      pk1 = *(const i32x4*)(Kh + (kb + srow+32)*HD + sseg*8);
      pv0 = *(const i32x4*)(Vh + (size_t)srow*SEQ + kb + sseg*8);
      pv1 = *(const i32x4*)(Vh + (size_t)(srow+32)*SEQ + kb + sseg*8);
    }
    if (kt < myNt) {
      const char* Kb = (const char*)Ks[cur];
      const char* Vb = (const char*)Vs[cur];
      // ---- QK^T (swapped): c[kc] = K-tile-half kc x Q  -> S^T[key][q]
      f32x16 c[2];
      #pragma unroll
      for (int kc = 0; kc < 2; ++kc) {
        f32x16 acc = {};
        #pragma unroll
        for (int ds = 0; ds < 4; ++ds) {
          const int row = kc*32 + qcol;   // key row
          short8 kf = *(const short8*)(Kb + row*128 + ((ds*32 + hi*16) ^ ((row & 7) << 4)));
          acc = __builtin_amdgcn_mfma_f32_32x32x16_bf16(kf, qf[ds], acc, 0, 0, 0);
        }
        c[kc] = acc;
      }
      // ---- causal mask (diagonal tile only)
      if (kt == myNt - 1) {
        const int q = qw + qcol;
        #pragma unroll
        for (int kc = 0; kc < 2; ++kc)
          #pragma unroll
          for (int r = 0; r < 16; ++r) {
            int key = kt*64 + kc*32 + (r & 3) + 8*(r >> 2) + 4*hi;
            if (key > q) c[kc][r] = -1e30f;
          }
      }
      // ---- online softmax, per-lane (q = qcol); halves combined via shfl_xor(32)
      float mx = c[0][0];
      #pragma unroll
      for (int r = 1; r < 16; ++r) mx = fmaxf(mx, c[0][r]);
      #pragma unroll
      for (int r = 0; r < 16; ++r) mx = fmaxf(mx, c[1][r]);
      mx = fmaxf(mx, __shfl_xor(mx, 32));
      float nm = fmaxf(m_r, mx);
      if (__any(nm > m_r)) {            // rescale only when some lane's max grew
        float corr = __expf(m_r - nm);
        m_r = nm;
        l_r *= corr;
        #pragma unroll
        for (int dc = 0; dc < 2; ++dc)
          #pragma unroll
          for (int r = 0; r < 16; ++r) o[dc][r] *= corr;
      }
      float sum = 0.f;
      #pragma unroll
      for (int kc = 0; kc < 2; ++kc)
        #pragma unroll
        for (int r = 0; r < 16; ++r) {
          float p = __expf(c[kc][r] - m_r);
          c[kc][r] = p;
          sum += p;
        }
      sum += __shfl_xor(sum, 32);
      l_r += sum;
      // ---- pack P to bf16 pairs: U[g][p] holds keys 8g+4hi+2p, +1
      unsigned U[8][2];
      #pragma unroll
      for (int g = 0; g < 8; ++g) {
        const int fc = g >> 2, gq = g & 3;
        U[g][0] = cvtpk_bf16(c[fc][4*gq + 0], c[fc][4*gq + 1]);
        U[g][1] = cvtpk_bf16(c[fc][4*gq + 2], c[fc][4*gq + 3]);
      }
      // ---- PV (swapped): O^T += V-frag x P-frag, per 16-key slice ks
      #pragma unroll
      for (int ks = 0; ks < 4; ++ks) {
        unsigned j0 = U[2*ks][0], j2 = U[2*ks+1][0];
        perm32swap(j0, j2);   // j0: B reg0 (k +0,1); j2: B reg2 (k +4,5)
        unsigned j1 = U[2*ks][1], j3 = U[2*ks+1][1];
        perm32swap(j1, j3);   // j1: B reg1 (k +2,3); j3: B reg3 (k +6,7)
        union { unsigned u[4]; short8 s; } pf;
        pf.u[0] = j0; pf.u[1] = j1; pf.u[2] = j2; pf.u[3] = j3;
        #pragma unroll
        for (int dc = 0; dc < 2; ++dc) {
          const int row = dc*32 + qcol;   // d row
          short8 vf = *(const short8*)(Vb + row*128 + ((ks*32 + hi*16) ^ ((row & 7) << 4)));
          o[dc] = __builtin_amdgcn_mfma_f32_32x32x16_bf16(vf, pf.s, o[dc], 0, 0, 0);
        }
      }
    }
    __syncthreads();                  // everyone done reading buf[cur]
    if (kt + 1 < nt) {
      *(i32x4*)((char*)Ks[cur^1] + srow*128 + swz) = pk0;
      *(i32x4*)((char*)Ks[cur^1] + (srow+32)*128 + swz) = pk1;
      *(i32x4*)((char*)Vs[cur^1] + srow*128 + swz) = pv0;
      *(i32x4*)((char*)Vs[cur^1] + (srow+32)*128 + swz) = pv1;
    }
    __syncthreads();                  // next buffer ready
  }

  // ---- epilogue: O^T / l, scatter to AO[b, q, h*64+d]
  const float inv = 1.0f / l_r;
  const size_t rowbase = ((size_t)b*SEQ + qw + qcol) * D_MODEL + h*HD;
  #pragma unroll
  for (int dc = 0; dc < 2; ++dc)
    #pragma unroll
    for (int r = 0; r < 16; ++r) {
      int d = dc*32 + (r & 3) + 8*(r >> 2) + 4*hi;
      AO[rowbase + d] = f2bf(o[dc][r] * inv);
    }
}

extern "C" void kernel_launch(void* const* d_in, const int* in_sizes, int n_in,
                              void* d_out, int out_size, void* d_ws, size_t ws_size,
                              hipStream_t stream)
{
  const float* x  = (const float*)d_in[0];
  const int* posi = (const int*)d_in[1];
  const float* wq = (const float*)d_in[2];
  const float* wk = (const float*)d_in[3];
  const float* wv = (const float*)d_in[4];
  const float* wo = (const float*)d_in[5];
  float* out = (float*)d_out;

  char* ws = (char*)d_ws;
  size_t off = 0;
  auto alloc = [&](size_t bytes) {
    char* p = ws + off;
    off += (bytes + 255) & ~(size_t)255;
    return p;
  };
  unsigned short* xb  = (unsigned short*)alloc((size_t)MTOT*D_MODEL*2);
  unsigned short* wqb = (unsigned short*)alloc((size_t)D_MODEL*D_MODEL*2);
  unsigned short* wkb = (unsigned short*)alloc((size_t)D_MODEL*D_MODEL*2);
  unsigned short* wvb = (unsigned short*)alloc((size_t)D_MODEL*D_MODEL*2);
  unsigned short* wob = (unsigned short*)alloc((size_t)D_MODEL*D_MODEL*2);
  unsigned short* Qb  = (unsigned short*)alloc((size_t)BHN*SEQ*HD*2);
  unsigned short* Kb  = (unsigned short*)alloc((size_t)BHN*SEQ*HD*2);
  unsigned short* VTb = (unsigned short*)alloc((size_t)BHN*HD*SEQ*2);
  unsigned short* AOb = (unsigned short*)alloc((size_t)MTOT*D_MODEL*2);
  float* ct = (float*)alloc((size_t)SEQ*32*4);
  float* st = (float*)alloc((size_t)SEQ*32*4);

  k_f2bf4<<<(MTOT*D_MODEL/4 + 255)/256, 256, 0, stream>>>(x, xb, MTOT*D_MODEL/4);
  k_f2bf4<<<(D_MODEL*D_MODEL/4 + 255)/256, 256, 0, stream>>>(wq, wqb, D_MODEL*D_MODEL/4);
  k_f2bf4<<<(D_MODEL*D_MODEL/4 + 255)/256, 256, 0, stream>>>(wk, wkb, D_MODEL*D_MODEL/4);
  k_f2bf4<<<(D_MODEL*D_MODEL/4 + 255)/256, 256, 0, stream>>>(wv, wvb, D_MODEL*D_MODEL/4);
  k_f2bf4<<<(D_MODEL*D_MODEL/4 + 255)/256, 256, 0, stream>>>(wo, wob, D_MODEL*D_MODEL/4);
  k_ropetab<<<(SEQ*32 + 255)/256, 256, 0, stream>>>(posi, ct, st);

  k_gemm_qkv<<<dim3(MTOT/128, D_MODEL/128, 3), 256, 0, stream>>>(xb, wqb, wkb, wvb, Qb, Kb, VTb);
  k_rope<<<(BHN*SEQ*32)/256, 256, 0, stream>>>(Qb, Kb, ct, st);
  k_attn<<<dim3(32, BHN), 256, 0, stream>>>(Qb, Kb, VTb, AOb);
  k_gemm_wo<<<dim3(MTOT/128, D_MODEL/128), 256, 0, stream>>>(AOb, wob, out);
}